// Round 2
// baseline (548.933 us; speedup 1.0000x reference)
//
#include <hip/hip_runtime.h>
#include <stdint.h>

// CTC loss forward, MI355X.
// Phase 1 (k_gather_exp): block per (b, 8-row chunk); each thread's target
//   label is CONSTANT across t, so hold it in a register and issue 8
//   independent row gathers before any use (8x MLP vs the old one-row
//   blocks, which were latency-bound: LDS-staging the row changed nothing,
//   so transactions were never the limit). No LDS, no barriers.
//   El[b][t][d] = exp(lp[b,t,tgt[b,d]]), Eb[b][t] = exp(lp[b,t,0]).
// Phase 2 (k_ctc_alpha): one wave per sample; linear-domain alpha with
//   per-lane power-of-2 offsets (renorm every 4 steps, no transcendentals).
//   Emissions streamed global->REGISTERS via a 16-slot rotating pipeline of
//   NAMED registers (macro-generated P0..P15/Q0..Q15 — the float4 pel[16]
//   array version compiled to VGPR_Count=68 < the 80-reg payload, i.e. the
//   array went to scratch and every step ate ~200cy load latency; named
//   statically-indexed scalars cannot go to scratch without spilling).
//   __launch_bounds__(64,1): 32 blocks total on a 256-CU chip — occupancy
//   is irrelevant, give the allocator the full 512-VGPR budget.
//   Cross-lane shift-by-1 via DPP wave_shr1 (VALU latency, not DS).
// Phase 3 (k_reduce): mean over batch of nll/target_length.

#define LN2F 0.69314718055994530942f
#define PD 16  // register pipeline depth (steps)
#define CH 8   // phase-1 rows per block

#define X16(M) M(0) M(1) M(2) M(3) M(4) M(5) M(6) M(7) \
               M(8) M(9) M(10) M(11) M(12) M(13) M(14) M(15)

// lane i <- lane i-1, lane 0 <- 0 (DPP wave_shr1, bound_ctrl=1)
__device__ __forceinline__ float shr1f(float x) {
  return __int_as_float(
      __builtin_amdgcn_update_dpp(0, __float_as_int(x), 0x138, 0xF, 0xF, true));
}
__device__ __forceinline__ int shr1i(int x) {
  return __builtin_amdgcn_update_dpp(0, x, 0x138, 0xF, 0xF, true);
}

__global__ __launch_bounds__(256) void k_gather_exp(
    const float* __restrict__ lp, const int* __restrict__ tgt,
    const int* __restrict__ ilen, float* __restrict__ El,
    float* __restrict__ Eb, int T, int V, int S) {
  const int b = blockIdx.y;
  const int Tb = ilen[b];
  const int t0 = blockIdx.x * CH;
  if (t0 >= Tb) return;  // phase 2 never reads t >= T_b
  const int tid = threadIdx.x;          // S == 256 == blockDim
  const int lab = tgt[b * S + tid];     // constant across all rows
  const float* rb = lp + (size_t)b * T * V;
  const int nr = min(CH, Tb - t0);

  if (nr == CH) {  // full chunk: 8 independent loads in flight, then uses
    float v[CH];
#pragma unroll
    for (int j = 0; j < CH; ++j)
      v[j] = rb[(size_t)(t0 + j) * V + lab];
    const float bl = (tid < CH) ? rb[(size_t)(t0 + tid) * V] : 0.0f;
#pragma unroll
    for (int j = 0; j < CH; ++j)
      El[((size_t)b * T + t0 + j) * 256 + tid] = __expf(v[j]);
    if (tid < CH) Eb[(size_t)b * T + t0 + tid] = __expf(bl);
  } else {  // ragged tail at t = Tb
#pragma unroll
    for (int j = 0; j < CH; ++j)
      if (j < nr)
        El[((size_t)b * T + t0 + j) * 256 + tid] =
            __expf(rb[(size_t)(t0 + j) * V + lab]);
    if (tid < nr) Eb[(size_t)b * T + t0 + tid] = __expf(rb[(size_t)(t0 + tid) * V]);
  }
}

__global__ __launch_bounds__(64, 1) void k_ctc_alpha(
    const float* __restrict__ El, const float* __restrict__ Eb,
    const int* __restrict__ tgt, const int* __restrict__ ilen,
    const int* __restrict__ tlen, float* __restrict__ nll_out, int T, int S) {
  const int b = blockIdx.x;
  const int lane = threadIdx.x;
  const bool l0 = (lane == 0);

  const int Tb = ilen[b];
  const int U = tlen[b];
  const int Tbm1 = Tb - 1;

  // skip flags per pair p = 4*lane + j
  const int4 tg = *(const int4*)(tgt + (size_t)b * S + 4 * lane);
  const int tprev = __shfl_up(tg.w, 1);
  const float sk0 = (l0 || tg.x != tprev) ? 1.0f : 0.0f;
  const float sk1 = (tg.y != tg.x) ? 1.0f : 0.0f;
  const float sk2 = (tg.z != tg.y) ? 1.0f : 0.0f;
  const float sk3 = (tg.w != tg.z) ? 1.0f : 0.0f;

  const float* Elb = El + (size_t)b * T * 256;
  const float* Ebb = Eb + (size_t)b * T;

  // lane owns pairs p=4*lane..4*lane+3 (states 2p+1 label, 2p+2 blank);
  // a0 = state 0 (lane 0 only). true alpha = a * 2^o (per-lane offset).
  // t = 0 init: only states 0,1 live.
  float a0 = l0 ? Ebb[0] : 0.0f;
  float aL0 = l0 ? Elb[0] : 0.0f;
  float aL1 = 0, aL2 = 0, aL3 = 0;
  float aB0 = 0, aB1 = 0, aB2 = 0, aB3 = 0;
  int o = 0;
  float s = 1.0f;  // 2^(o_left - o)

  auto stepf = [&](float4 el, float eb) {  // generic step (t > 0)
    float pL = shr1f(aL3) * s;  // state 2p-1 for p = 4*lane
    float pB = shr1f(aB3) * s;  // state 2p
    pL = l0 ? 0.0f : pL;
    pB = l0 ? a0 : pB;
    const float nB0 = (aB0 + aL0) * eb;
    const float nB1 = (aB1 + aL1) * eb;
    const float nB2 = (aB2 + aL2) * eb;
    const float nB3 = (aB3 + aL3) * eb;
    const float nL0 = (aL0 + fmaf(sk0, pL, pB)) * el.x;
    const float nL1 = (aL1 + fmaf(sk1, aL0, aB0)) * el.y;
    const float nL2 = (aL2 + fmaf(sk2, aL1, aB1)) * el.z;
    const float nL3 = (aL3 + fmaf(sk3, aL2, aB2)) * el.w;
    a0 *= eb;
    aL0 = nL0; aL1 = nL1; aL2 = nL2; aL3 = nL3;
    aB0 = nB0; aB1 = nB1; aB2 = nB2; aB3 = nB3;
  };
  auto renorm = [&]() {  // per-lane power-of-2 rescale (no transcendentals)
    float m = fmaxf(fmaxf(fmaxf(aL0, aL1), fmaxf(aL2, aL3)),
                    fmaxf(fmaxf(aB0, aB1), fmaxf(aB2, aB3)));
    m = fmaxf(m, a0);
    const bool nz = (m > 0.0f);
    const int mk = nz ? (((__float_as_int(m) >> 23) & 0xff) - 126) : 0;
    const int ocand = o + mk;
    const int oleft = shr1i(ocand);
    o = (nz || l0) ? ocand : oleft;  // zero lanes adopt left offset
    const float sc = nz ? __int_as_float((127 - mk) << 23) : 1.0f;
    aL0 *= sc; aL1 *= sc; aL2 *= sc; aL3 *= sc;
    aB0 *= sc; aB1 *= sc; aB2 *= sc; aB3 *= sc;
    a0 *= sc;
    int d = shr1i(o) - o;
    d = max(-126, min(126, d));
    s = __int_as_float((d + 127) << 23);  // 2^d
  };

  const int lo4 = 4 * lane;

  // 16-slot register pipeline, NAMED slots (never an indexed array).
  // Slot j holds emissions for row t = base + j.
#define PIPE_DECL(j) float4 P##j; float Q##j;
  X16(PIPE_DECL)

  // prologue: rows 1..16 (Tb >= 17 always holds: ilen >= 1500)
#define PIPE_LOAD(j) {                                                  \
    const int r_ = min((j) + 1, Tbm1);                                  \
    P##j = *(const float4*)(Elb + ((size_t)r_ << 8) + lo4);             \
    Q##j = Ebb[r_]; }
  X16(PIPE_LOAD)

  const int R = Tbm1;         // generic steps t = 1..Tb-1
  const int nfull = R >> 4;
  const int rem = R & 15;

  for (int k = 0; k < nfull; ++k) {
    const int base = 1 + (k << 4);
    // t = base + j, base ≡ 1 (mod 16) → (t&3)==3 ⇔ (j&3)==2
#define PIPE_STEP(j) {                                                  \
      const float4 el_ = P##j;                                          \
      const float eb_ = Q##j;                                           \
      const int r_ = min(base + PD + (j), Tbm1);                        \
      P##j = *(const float4*)(Elb + ((size_t)r_ << 8) + lo4);           \
      Q##j = Ebb[r_];                                                   \
      stepf(el_, eb_);                                                  \
      if (((j) & 3) == 2) renorm(); }
    X16(PIPE_STEP)
  }
  // tail: remaining rem steps, slots 0..rem-1 already loaded
#define PIPE_TAIL(j) if ((j) < rem) {                                   \
    stepf(P##j, Q##j);                                                  \
    if (((j) & 3) == 2) renorm(); }
  X16(PIPE_TAIL)

  // alpha_{Tb-1} at states 2U (pair U-1 blank) and 2U-1 (pair U-1 label)
  if (lane == ((U - 1) >> 2)) {
    const int j = (U - 1) & 3;
    float sv;
    if (j == 0)      sv = aL0 + aB0;
    else if (j == 1) sv = aL1 + aB1;
    else if (j == 2) sv = aL2 + aB2;
    else             sv = aL3 + aB3;
    float nll = -LN2F * (__log2f(sv) + (float)o);
    if (!(nll < 5e29f)) nll = 0.0f;  // zero_infinity (catches NaN/inf)
    nll_out[b] = nll / (float)U;
  }
}

__global__ __launch_bounds__(64) void k_reduce(const float* __restrict__ nll,
                                               float* __restrict__ out,
                                               int B) {
  float v = 0.0f;
  for (int i = threadIdx.x; i < B; i += 64) v += nll[i];
  for (int off = 32; off > 0; off >>= 1) v += __shfl_down(v, off);
  if (threadIdx.x == 0) out[0] = v / (float)B;
}

extern "C" void kernel_launch(void* const* d_in, const int* in_sizes, int n_in,
                              void* d_out, int out_size, void* d_ws,
                              size_t ws_size, hipStream_t stream) {
  const float* lp = (const float*)d_in[0];
  const int* tgt = (const int*)d_in[1];
  const int* ilen = (const int*)d_in[2];
  const int* tlen = (const int*)d_in[3];

  const int B = in_sizes[2];
  const int S = in_sizes[1] / B;                               // 256
  const int V = 1024;                                          // fixed by problem
  const int T = (int)((size_t)in_sizes[0] / ((size_t)B * V));  // 2000

  float* El = (float*)d_ws;                 // B*T*S f32
  float* Eb = El + (size_t)B * T * S;       // B*T f32
  float* nw = Eb + (size_t)B * T;           // B f32

  dim3 g1((T + CH - 1) / CH, B);
  k_gather_exp<<<g1, 256, 0, stream>>>(lp, tgt, ilen, El, Eb, T, V, S);
  k_ctc_alpha<<<B, 64, 0, stream>>>(El, Eb, tgt, ilen, tlen, nw, T, S);
  k_reduce<<<1, 64, 0, stream>>>(nw, (float*)d_out, B);
}

// Round 5
// 536.016 us; speedup vs baseline: 1.0241x; 1.0241x over previous
//
#include <hip/hip_runtime.h>
#include <stdint.h>

// CTC loss forward, MI355X.
// Phase 1 (k_gather_exp): block per (b,t) row; direct global gather of the
//   256 target emissions + blank, exp(), coalesced compact store. (Round-0
//   form; LDS staging and 8-row chunking both measured neutral-to-worse.)
// Phase 2 (k_ctc_alpha): one wave per sample; linear-domain alpha with
//   per-lane power-of-2 offsets (renorm every 4 steps, no transcendentals).
//   Emission streaming: DOUBLE-BUFFERED 8-row batches in NAMED registers,
//   plain-C loads (compiler-managed, provably-correct waitcnts) with
//   __builtin_amdgcn_sched_barrier(0) pinning each batch's issue point so
//   the scheduler cannot sink the loads to their uses (rounds 1-2: sunk
//   loads collapsed the pipeline to depth 1, VGPR_Count=68, ~250cy exposed
//   latency/step; round 3's hand-counted asm ring corrupted data — register-
//   level reordering around opaque asm is unverifiable, abandoned).
//   Consume A (8 steps) | refill A | SB(0) | consume B | refill B | SB(0):
//   8 steps x ~50cy between issue and first use covers ~250cy L2 latency.
//   __launch_bounds__(64,1): 32 waves on the whole chip, occupancy moot,
//   give the allocator the full VGPR budget for the 80-reg payload.
// Phase 3 (k_reduce): mean over batch of nll/target_length.
// (Round 4 was an infra failure — this resubmits the untested round-4 kernel.)

#define LN2F 0.69314718055994530942f

#define X8(M) M(0) M(1) M(2) M(3) M(4) M(5) M(6) M(7)

// lane i <- lane i-1, lane 0 <- 0 (DPP wave_shr1, bound_ctrl=1)
__device__ __forceinline__ float shr1f(float x) {
  return __int_as_float(
      __builtin_amdgcn_update_dpp(0, __float_as_int(x), 0x138, 0xF, 0xF, true));
}
__device__ __forceinline__ int shr1i(int x) {
  return __builtin_amdgcn_update_dpp(0, x, 0x138, 0xF, 0xF, true);
}

__global__ __launch_bounds__(256) void k_gather_exp(
    const float* __restrict__ lp, const int* __restrict__ tgt,
    const int* __restrict__ ilen, float* __restrict__ El,
    float* __restrict__ Eb, int T, int V, int S) {
  const int b = blockIdx.y;
  const int t = blockIdx.x;
  if (t >= ilen[b]) return;  // phase 2 never reads t >= T_b
  const int tid = threadIdx.x;               // S == 256 == blockDim
  const int lab = tgt[b * S + tid];
  const float* row = lp + ((size_t)b * T + t) * V;
  El[((size_t)b * T + t) * S + tid] = __expf(row[lab]);
  if (tid == 0) Eb[(size_t)b * T + t] = __expf(row[0]);
}

__global__ __launch_bounds__(64, 1) void k_ctc_alpha(
    const float* __restrict__ El, const float* __restrict__ Eb,
    const int* __restrict__ tgt, const int* __restrict__ ilen,
    const int* __restrict__ tlen, float* __restrict__ nll_out, int T, int S) {
  const int b = blockIdx.x;
  const int lane = threadIdx.x;
  const bool l0 = (lane == 0);

  const int Tb = ilen[b];
  const int U = tlen[b];
  const int Tbm1 = Tb - 1;

  // skip flags per pair p = 4*lane + j
  const int4 tg = *(const int4*)(tgt + (size_t)b * S + 4 * lane);
  const int tprev = __shfl_up(tg.w, 1);
  const float sk0 = (l0 || tg.x != tprev) ? 1.0f : 0.0f;
  const float sk1 = (tg.y != tg.x) ? 1.0f : 0.0f;
  const float sk2 = (tg.z != tg.y) ? 1.0f : 0.0f;
  const float sk3 = (tg.w != tg.z) ? 1.0f : 0.0f;

  const float* Elb = El + (size_t)b * T * 256;
  const float* Ebb = Eb + (size_t)b * T;

  // lane owns pairs p=4*lane..4*lane+3 (states 2p+1 label, 2p+2 blank);
  // a0 = state 0 (lane 0 only). true alpha = a * 2^o (per-lane offset).
  float a0 = l0 ? Ebb[0] : 0.0f;
  float aL0 = l0 ? Elb[0] : 0.0f;
  float aL1 = 0, aL2 = 0, aL3 = 0;
  float aB0 = 0, aB1 = 0, aB2 = 0, aB3 = 0;
  int o = 0;
  float s = 1.0f;  // 2^(o_left - o)

  auto stepf = [&](float4 el, float eb) {  // generic step (t > 0)
    float pL = shr1f(aL3) * s;  // state 2p-1 for p = 4*lane
    float pB = shr1f(aB3) * s;  // state 2p
    pL = l0 ? 0.0f : pL;
    pB = l0 ? a0 : pB;
    const float nB0 = (aB0 + aL0) * eb;
    const float nB1 = (aB1 + aL1) * eb;
    const float nB2 = (aB2 + aL2) * eb;
    const float nB3 = (aB3 + aL3) * eb;
    const float nL0 = (aL0 + fmaf(sk0, pL, pB)) * el.x;
    const float nL1 = (aL1 + fmaf(sk1, aL0, aB0)) * el.y;
    const float nL2 = (aL2 + fmaf(sk2, aL1, aB1)) * el.z;
    const float nL3 = (aL3 + fmaf(sk3, aL2, aB2)) * el.w;
    a0 *= eb;
    aL0 = nL0; aL1 = nL1; aL2 = nL2; aL3 = nL3;
    aB0 = nB0; aB1 = nB1; aB2 = nB2; aB3 = nB3;
  };
  auto renorm = [&]() {  // per-lane power-of-2 rescale (no transcendentals)
    float m = fmaxf(fmaxf(fmaxf(aL0, aL1), fmaxf(aL2, aL3)),
                    fmaxf(fmaxf(aB0, aB1), fmaxf(aB2, aB3)));
    m = fmaxf(m, a0);
    const bool nz = (m > 0.0f);
    const int mk = nz ? (((__float_as_int(m) >> 23) & 0xff) - 126) : 0;
    const int ocand = o + mk;
    const int oleft = shr1i(ocand);
    o = (nz || l0) ? ocand : oleft;  // zero lanes adopt left offset
    const float sc = nz ? __int_as_float((127 - mk) << 23) : 1.0f;
    aL0 *= sc; aL1 *= sc; aL2 *= sc; aL3 *= sc;
    aB0 *= sc; aB1 *= sc; aB2 *= sc; aB3 *= sc;
    a0 *= sc;
    int d = shr1i(o) - o;
    d = max(-126, min(126, d));
    s = __int_as_float((d + 127) << 23);  // 2^d
  };

  const int lo4 = 4 * lane;

  // Double-buffered batches of 8 rows in named registers.
#define DECL_A(j) float4 A##j; float eA##j;
#define DECL_B(j) float4 B##j; float eB##j;
  X8(DECL_A)
  X8(DECL_B)

#define LOAD_A(j) {                                                      \
    const int r_ = min(rbase + (j), Tbm1);                               \
    A##j = *(const float4*)(Elb + ((size_t)r_ << 8) + lo4);              \
    eA##j = Ebb[r_]; }
#define LOAD_B(j) {                                                      \
    const int r_ = min(rbase + (j), Tbm1);                               \
    B##j = *(const float4*)(Elb + ((size_t)r_ << 8) + lo4);              \
    eB##j = Ebb[r_]; }

  // prologue: A <- rows 1..8, B <- rows 9..16 (Tb >= 1500 per problem spec)
  { const int rbase = 1; X8(LOAD_A) }
  __builtin_amdgcn_sched_barrier(0);
  { const int rbase = 9; X8(LOAD_B) }
  __builtin_amdgcn_sched_barrier(0);

  const int R = Tbm1;  // generic steps t = 1..Tb-1
  const int nfull = R >> 4;
  const int rem = R & 15;

  // t = base + off, base ≡ 1 (mod 16) → (t&3)==3 ⇔ (off&3)==2; for batch B
  // off = 8+j and (8+j)&3 == j&3, so both batches renorm at (j&3)==2.
#define STEP_A(j) { stepf(A##j, eA##j); if (((j) & 3) == 2) renorm(); }
#define STEP_B(j) { stepf(B##j, eB##j); if (((j) & 3) == 2) renorm(); }

  for (int k = 0; k < nfull; ++k) {
    const int base = 1 + (k << 4);
    X8(STEP_A)                                     // consume rows base..base+7
    { const int rbase = base + 16; X8(LOAD_A) }    // refill A: rows +16..+23
    __builtin_amdgcn_sched_barrier(0);
    X8(STEP_B)                                     // consume rows base+8..base+15
    { const int rbase = base + 24; X8(LOAD_B) }    // refill B: rows +24..+31
    __builtin_amdgcn_sched_barrier(0);
  }

  // tail: rem rows remain; A holds rows 1+16*nfull+j, B the next 8
#define TAIL_A(j) if ((j) < rem) STEP_A(j)
#define TAIL_B(j) if ((j) + 8 < rem) STEP_B(j)
  X8(TAIL_A)
  X8(TAIL_B)

  // alpha_{Tb-1} at states 2U (pair U-1 blank) and 2U-1 (pair U-1 label)
  if (lane == ((U - 1) >> 2)) {
    const int j = (U - 1) & 3;
    float sv;
    if (j == 0)      sv = aL0 + aB0;
    else if (j == 1) sv = aL1 + aB1;
    else if (j == 2) sv = aL2 + aB2;
    else             sv = aL3 + aB3;
    float nll = -LN2F * (__log2f(sv) + (float)o);
    if (!(nll < 5e29f)) nll = 0.0f;  // zero_infinity (catches NaN/inf)
    nll_out[b] = nll / (float)U;
  }
}

__global__ __launch_bounds__(64) void k_reduce(const float* __restrict__ nll,
                                               float* __restrict__ out,
                                               int B) {
  float v = 0.0f;
  for (int i = threadIdx.x; i < B; i += 64) v += nll[i];
  for (int off = 32; off > 0; off >>= 1) v += __shfl_down(v, off);
  if (threadIdx.x == 0) out[0] = v / (float)B;
}

extern "C" void kernel_launch(void* const* d_in, const int* in_sizes, int n_in,
                              void* d_out, int out_size, void* d_ws,
                              size_t ws_size, hipStream_t stream) {
  const float* lp = (const float*)d_in[0];
  const int* tgt = (const int*)d_in[1];
  const int* ilen = (const int*)d_in[2];
  const int* tlen = (const int*)d_in[3];

  const int B = in_sizes[2];
  const int S = in_sizes[1] / B;                               // 256
  const int V = 1024;                                          // fixed by problem
  const int T = (int)((size_t)in_sizes[0] / ((size_t)B * V));  // 2000

  float* El = (float*)d_ws;                 // B*T*S f32
  float* Eb = El + (size_t)B * T * S;       // B*T f32
  float* nw = Eb + (size_t)B * T;           // B f32

  dim3 g1(T, B);
  k_gather_exp<<<g1, 256, 0, stream>>>(lp, tgt, ilen, El, Eb, T, V, S);
  k_ctc_alpha<<<B, 64, 0, stream>>>(El, Eb, tgt, ilen, tlen, nw, T, S);
  k_reduce<<<1, 64, 0, stream>>>(nw, (float*)d_out, B);
}

// Round 7
// 513.876 us; speedup vs baseline: 1.0682x; 1.0431x over previous
//
#include <hip/hip_runtime.h>
#include <stdint.h>

// CTC loss forward, MI355X.
// Phase 1 (k_gather_exp): block per (b,t) row; direct global gather of the
//   256 target emissions + blank, exp(), coalesced compact store. (Round-0
//   form; LDS staging and 8-row chunking both measured neutral-to-worse.)
// Phase 2 (k_ctc_alpha): one wave per sample; linear-domain alpha with
//   per-lane power-of-2 offsets (renorm every 4 steps, no transcendentals).
//   Emission streaming: double-buffered 8-row batches in NAMED SCALAR
//   registers with REGISTER-FENCE materialization: empty `asm volatile`
//   with "+v" tied SCALAR operands (float4 operands are "tied indirect
//   register inputs" — unsupported, r6 compile fail) + "memory" clobber.
//   The tied outputs force the whole batch to be loaded and in-register at
//   the fence (compiler inserts its own exact waitcnt — correct by
//   construction); the memory clobber stops the NEXT batch's loads sinking
//   across the fence (the loophole that collapsed r1/r2/r5 to depth-1:
//   VGPR stuck at 68-72, ~250cy exposed latency/step). Worst case the
//   latency is batch-amortized (~250cy per 8 steps); best case hidden.
//   Loads stay plain-C via a float4 temp (dwordx4 preserved, components
//   SSA-extracted into the named scalars).
//   __launch_bounds__(64,1): 32 waves on the whole chip, occupancy moot.
// Phase 3 (k_reduce): mean over batch of nll/target_length.

#define LN2F 0.69314718055994530942f

#define X8(M) M(0) M(1) M(2) M(3) M(4) M(5) M(6) M(7)

// lane i <- lane i-1, lane 0 <- 0 (DPP wave_shr1, bound_ctrl=1)
__device__ __forceinline__ float shr1f(float x) {
  return __int_as_float(
      __builtin_amdgcn_update_dpp(0, __float_as_int(x), 0x138, 0xF, 0xF, true));
}
__device__ __forceinline__ int shr1i(int x) {
  return __builtin_amdgcn_update_dpp(0, x, 0x138, 0xF, 0xF, true);
}

__global__ __launch_bounds__(256) void k_gather_exp(
    const float* __restrict__ lp, const int* __restrict__ tgt,
    const int* __restrict__ ilen, float* __restrict__ El,
    float* __restrict__ Eb, int T, int V, int S) {
  const int b = blockIdx.y;
  const int t = blockIdx.x;
  if (t >= ilen[b]) return;  // phase 2 never reads t >= T_b
  const int tid = threadIdx.x;               // S == 256 == blockDim
  const int lab = tgt[b * S + tid];
  const float* row = lp + ((size_t)b * T + t) * V;
  El[((size_t)b * T + t) * S + tid] = __expf(row[lab]);
  if (tid == 0) Eb[(size_t)b * T + t] = __expf(row[0]);
}

__global__ __launch_bounds__(64, 1) void k_ctc_alpha(
    const float* __restrict__ El, const float* __restrict__ Eb,
    const int* __restrict__ tgt, const int* __restrict__ ilen,
    const int* __restrict__ tlen, float* __restrict__ nll_out, int T, int S) {
  const int b = blockIdx.x;
  const int lane = threadIdx.x;
  const bool l0 = (lane == 0);

  const int Tb = ilen[b];
  const int U = tlen[b];
  const int Tbm1 = Tb - 1;

  // skip flags per pair p = 4*lane + j
  const int4 tg = *(const int4*)(tgt + (size_t)b * S + 4 * lane);
  const int tprev = __shfl_up(tg.w, 1);
  const float sk0 = (l0 || tg.x != tprev) ? 1.0f : 0.0f;
  const float sk1 = (tg.y != tg.x) ? 1.0f : 0.0f;
  const float sk2 = (tg.z != tg.y) ? 1.0f : 0.0f;
  const float sk3 = (tg.w != tg.z) ? 1.0f : 0.0f;

  const float* Elb = El + (size_t)b * T * 256;
  const float* Ebb = Eb + (size_t)b * T;

  // lane owns pairs p=4*lane..4*lane+3 (states 2p+1 label, 2p+2 blank);
  // a0 = state 0 (lane 0 only). true alpha = a * 2^o (per-lane offset).
  float a0 = l0 ? Ebb[0] : 0.0f;
  float aL0 = l0 ? Elb[0] : 0.0f;
  float aL1 = 0, aL2 = 0, aL3 = 0;
  float aB0 = 0, aB1 = 0, aB2 = 0, aB3 = 0;
  int o = 0;
  float s = 1.0f;  // 2^(o_left - o)

  auto stepf = [&](float ex, float ey, float ez, float ew, float eb) {
    float pL = shr1f(aL3) * s;  // state 2p-1 for p = 4*lane
    float pB = shr1f(aB3) * s;  // state 2p
    pL = l0 ? 0.0f : pL;
    pB = l0 ? a0 : pB;
    const float nB0 = (aB0 + aL0) * eb;
    const float nB1 = (aB1 + aL1) * eb;
    const float nB2 = (aB2 + aL2) * eb;
    const float nB3 = (aB3 + aL3) * eb;
    const float nL0 = (aL0 + fmaf(sk0, pL, pB)) * ex;
    const float nL1 = (aL1 + fmaf(sk1, aL0, aB0)) * ey;
    const float nL2 = (aL2 + fmaf(sk2, aL1, aB1)) * ez;
    const float nL3 = (aL3 + fmaf(sk3, aL2, aB2)) * ew;
    a0 *= eb;
    aL0 = nL0; aL1 = nL1; aL2 = nL2; aL3 = nL3;
    aB0 = nB0; aB1 = nB1; aB2 = nB2; aB3 = nB3;
  };
  auto renorm = [&]() {  // per-lane power-of-2 rescale (no transcendentals)
    float m = fmaxf(fmaxf(fmaxf(aL0, aL1), fmaxf(aL2, aL3)),
                    fmaxf(fmaxf(aB0, aB1), fmaxf(aB2, aB3)));
    m = fmaxf(m, a0);
    const bool nz = (m > 0.0f);
    const int mk = nz ? (((__float_as_int(m) >> 23) & 0xff) - 126) : 0;
    const int ocand = o + mk;
    const int oleft = shr1i(ocand);
    o = (nz || l0) ? ocand : oleft;  // zero lanes adopt left offset
    const float sc = nz ? __int_as_float((127 - mk) << 23) : 1.0f;
    aL0 *= sc; aL1 *= sc; aL2 *= sc; aL3 *= sc;
    aB0 *= sc; aB1 *= sc; aB2 *= sc; aB3 *= sc;
    a0 *= sc;
    int d = shr1i(o) - o;
    d = max(-126, min(126, d));
    s = __int_as_float((d + 127) << 23);  // 2^d
  };

  const int lo4 = 4 * lane;

  // Double-buffered batches of 8 rows in named SCALAR registers.
#define DECL_A(j) float A##j##x, A##j##y, A##j##z, A##j##w, eA##j;
#define DECL_B(j) float B##j##x, B##j##y, B##j##z, B##j##w, eB##j;
  X8(DECL_A)
  X8(DECL_B)

#define LOAD_A(j) {                                                      \
    const int r_ = min(rbase + (j), Tbm1);                               \
    const float4 t_ = *(const float4*)(Elb + ((size_t)r_ << 8) + lo4);   \
    A##j##x = t_.x; A##j##y = t_.y; A##j##z = t_.z; A##j##w = t_.w;      \
    eA##j = Ebb[r_]; }
#define LOAD_B(j) {                                                      \
    const int r_ = min(rbase + (j), Tbm1);                               \
    const float4 t_ = *(const float4*)(Elb + ((size_t)r_ << 8) + lo4);   \
    B##j##x = t_.x; B##j##y = t_.y; B##j##z = t_.z; B##j##w = t_.w;      \
    eB##j = Ebb[r_]; }

  // Register fences: tied scalar "+v" outputs force the whole batch to be
  // loaded and in-register HERE (compiler emits the exact waitcnt);
  // "memory" clobber stops the other batch's loads sinking across.
#define FENCE_A()                                                          \
  asm volatile(""                                                          \
      : "+v"(A0x), "+v"(A0y), "+v"(A0z), "+v"(A0w), "+v"(eA0),             \
        "+v"(A1x), "+v"(A1y), "+v"(A1z), "+v"(A1w), "+v"(eA1),             \
        "+v"(A2x), "+v"(A2y), "+v"(A2z), "+v"(A2w), "+v"(eA2),             \
        "+v"(A3x), "+v"(A3y), "+v"(A3z), "+v"(A3w), "+v"(eA3),             \
        "+v"(A4x), "+v"(A4y), "+v"(A4z), "+v"(A4w), "+v"(eA4),             \
        "+v"(A5x), "+v"(A5y), "+v"(A5z), "+v"(A5w), "+v"(eA5),             \
        "+v"(A6x), "+v"(A6y), "+v"(A6z), "+v"(A6w), "+v"(eA6),             \
        "+v"(A7x), "+v"(A7y), "+v"(A7z), "+v"(A7w), "+v"(eA7)              \
      :: "memory")
#define FENCE_B()                                                          \
  asm volatile(""                                                          \
      : "+v"(B0x), "+v"(B0y), "+v"(B0z), "+v"(B0w), "+v"(eB0),             \
        "+v"(B1x), "+v"(B1y), "+v"(B1z), "+v"(B1w), "+v"(eB1),             \
        "+v"(B2x), "+v"(B2y), "+v"(B2z), "+v"(B2w), "+v"(eB2),             \
        "+v"(B3x), "+v"(B3y), "+v"(B3z), "+v"(B3w), "+v"(eB3),             \
        "+v"(B4x), "+v"(B4y), "+v"(B4z), "+v"(B4w), "+v"(eB4),             \
        "+v"(B5x), "+v"(B5y), "+v"(B5z), "+v"(B5w), "+v"(eB5),             \
        "+v"(B6x), "+v"(B6y), "+v"(B6z), "+v"(B6w), "+v"(eB6),             \
        "+v"(B7x), "+v"(B7y), "+v"(B7z), "+v"(B7w), "+v"(eB7)              \
      :: "memory")

  // prologue: A <- rows 1..8, B <- rows 9..16 (Tb >= 1500 per problem spec)
  { const int rbase = 1; X8(LOAD_A) }
  { const int rbase = 9; X8(LOAD_B) }
  FENCE_A();

  const int R = Tbm1;  // generic steps t = 1..Tb-1
  const int nfull = R >> 4;
  const int rem = R & 15;

  // t = base + off, base ≡ 1 (mod 16) → (t&3)==3 ⇔ (off&3)==2; for batch B
  // off = 8+j and (8+j)&3 == j&3, so both batches renorm at (j&3)==2.
#define STEP_A(j) { stepf(A##j##x, A##j##y, A##j##z, A##j##w, eA##j);    \
                    if (((j) & 3) == 2) renorm(); }
#define STEP_B(j) { stepf(B##j##x, B##j##y, B##j##z, B##j##w, eB##j);    \
                    if (((j) & 3) == 2) renorm(); }

  for (int k = 0; k < nfull; ++k) {
    const int base = 1 + (k << 4);
    X8(STEP_A)                                   // consume rows base..base+7
    { const int rbase = base + 16; X8(LOAD_A) }  // issue A': rows +16..+23
    FENCE_B();                                   // B ready; A' in flight
    X8(STEP_B)                                   // consume rows base+8..base+15
    { const int rbase = base + 24; X8(LOAD_B) }  // issue B': rows +24..+31
    FENCE_A();                                   // A' ready; B' in flight
  }

  // tail: rem rows remain; A holds rows 1+16*nfull+j, B the next 8
#define TAIL_A(j) if ((j) < rem) STEP_A(j)
#define TAIL_B(j) if ((j) + 8 < rem) STEP_B(j)
  X8(TAIL_A)
  FENCE_B();
  X8(TAIL_B)

  // alpha_{Tb-1} at states 2U (pair U-1 blank) and 2U-1 (pair U-1 label)
  if (lane == ((U - 1) >> 2)) {
    const int j = (U - 1) & 3;
    float sv;
    if (j == 0)      sv = aL0 + aB0;
    else if (j == 1) sv = aL1 + aB1;
    else if (j == 2) sv = aL2 + aB2;
    else             sv = aL3 + aB3;
    float nll = -LN2F * (__log2f(sv) + (float)o);
    if (!(nll < 5e29f)) nll = 0.0f;  // zero_infinity (catches NaN/inf)
    nll_out[b] = nll / (float)U;
  }
}

__global__ __launch_bounds__(64) void k_reduce(const float* __restrict__ nll,
                                               float* __restrict__ out,
                                               int B) {
  float v = 0.0f;
  for (int i = threadIdx.x; i < B; i += 64) v += nll[i];
  for (int off = 32; off > 0; off >>= 1) v += __shfl_down(v, off);
  if (threadIdx.x == 0) out[0] = v / (float)B;
}

extern "C" void kernel_launch(void* const* d_in, const int* in_sizes, int n_in,
                              void* d_out, int out_size, void* d_ws,
                              size_t ws_size, hipStream_t stream) {
  const float* lp = (const float*)d_in[0];
  const int* tgt = (const int*)d_in[1];
  const int* ilen = (const int*)d_in[2];
  const int* tlen = (const int*)d_in[3];

  const int B = in_sizes[2];
  const int S = in_sizes[1] / B;                               // 256
  const int V = 1024;                                          // fixed by problem
  const int T = (int)((size_t)in_sizes[0] / ((size_t)B * V));  // 2000

  float* El = (float*)d_ws;                 // B*T*S f32
  float* Eb = El + (size_t)B * T * S;       // B*T f32
  float* nw = Eb + (size_t)B * T;           // B f32

  dim3 g1(T, B);
  k_gather_exp<<<g1, 256, 0, stream>>>(lp, tgt, ilen, El, Eb, T, V, S);
  k_ctc_alpha<<<B, 64, 0, stream>>>(El, Eb, tgt, ilen, tlen, nw, T, S);
  k_reduce<<<1, 64, 0, stream>>>(nw, (float*)d_out, B);
}